// Round 4
// baseline (73.167 us; speedup 1.0000x reference)
//
#include <hip/hip_runtime.h>

// Problem constants (from reference init_kwargs)
#define BB   64
#define KP   21
#define HH   256
#define KS   9
#define PADK 4   // KS/2

#define NPLANES          (BB * KP)          // 1344
#define F4_PER_PLANE     (HH * HH / 4)      // 16384 float4 per plane
#define BLOCKS_PER_PLANE 4
#define THREADS          256
#define F4_PER_THREAD    (F4_PER_PLANE / (BLOCKS_PER_PLANE * THREADS)) // 16

typedef float vfloat4 __attribute__((ext_vector_type(4)));  // native clang vector

// Fused zero + Gaussian-patch scatter, nontemporal stores (pure streaming
// write — avoid L2 dirty-line thrash). Each (b,k) plane has exactly one
// spike at (r,c); output = 10*kernel2d in the clipped 9x9 patch, 0 elsewhere.
// Every output element is written exactly once per call.
__global__ __launch_bounds__(THREADS)
void heatmap_fused_nt_kernel(const int* __restrict__ x,
                             const float* __restrict__ k2d,
                             vfloat4* __restrict__ out) {
    const int p   = blockIdx.x / BLOCKS_PER_PLANE;   // plane 0..1343
    const int sub = blockIdx.x % BLOCKS_PER_PLANE;
    const int t   = threadIdx.x;

    const int r = x[2 * p];
    const int c = x[2 * p + 1];

    vfloat4* plane = out + (size_t)p * F4_PER_PLANE;

#pragma unroll
    for (int ch = 0; ch < F4_PER_THREAD; ++ch) {
        // consecutive threads -> consecutive float4s (1 KiB / wave / store)
        const int f4   = sub * (F4_PER_PLANE / BLOCKS_PER_PLANE) + ch * THREADS + t;
        const int i    = f4 >> 6;          // row 0..255
        const int col0 = (f4 & 63) << 2;   // first col of this float4

        vfloat4 v = (vfloat4)0.0f;
        if (i >= r - PADK && i <= r + PADK &&
            col0 + 3 >= c - PADK && col0 <= c + PADK) {
            const int di = r - i + PADK;   // 0..8 guaranteed by row check
#pragma unroll
            for (int e = 0; e < 4; ++e) {
                const int dj = c - (col0 + e) + PADK;
                v[e] = (dj >= 0 && dj < KS) ? 10.0f * k2d[di * KS + dj] : 0.0f;
            }
        }
        __builtin_nontemporal_store(v, &plane[f4]);
    }
}

extern "C" void kernel_launch(void* const* d_in, const int* in_sizes, int n_in,
                              void* d_out, int out_size, void* d_ws, size_t ws_size,
                              hipStream_t stream) {
    const int*   x   = (const int*)d_in[0];    // [B, KP, 2] int32
    const float* k2d = (const float*)d_in[1];  // [KS, KS] float32
    vfloat4*     out = (vfloat4*)d_out;        // [B, KP, H, H] float32

    heatmap_fused_nt_kernel<<<NPLANES * BLOCKS_PER_PLANE, THREADS, 0, stream>>>(x, k2d, out);
}

// Round 5
// 68.310 us; speedup vs baseline: 1.0711x; 1.0711x over previous
//
#include <hip/hip_runtime.h>

// Problem constants (from reference init_kwargs)
#define BB   64
#define KP   21
#define HH   256
#define KS   9
#define PADK 4   // KS/2

#define NPLANES          (BB * KP)          // 1344
#define F4_PER_PLANE     (HH * HH / 4)      // 16384 float4 per plane
#define BLOCKS_PER_PLANE 4                  // 5376 blocks = 21/CU exactly
#define THREADS          256
#define F4_PER_SEG       (F4_PER_PLANE / BLOCKS_PER_PLANE)   // 4096
#define F4_PER_THREAD    (F4_PER_SEG / THREADS)              // 16

typedef float vfloat4 __attribute__((ext_vector_type(4)));

// Fused zero + Gaussian-patch scatter.
// Phase 1: branch-free fill-style zero stream (16 unconditional dwordx4
//          stores per thread) over this block's 64-row segment.
// Phase 2: __syncthreads (drains vmcnt(0) per wave before s_barrier, so all
//          zero stores are issued before any patch store), then threads 0..80
//          overwrite the clipped 9x9 patch elements that land in this segment.
// Every output element written deterministically each call.
__global__ __launch_bounds__(THREADS)
void heatmap_fused2_kernel(const int* __restrict__ x,
                           const float* __restrict__ k2d,
                           vfloat4* __restrict__ out) {
    const int p   = blockIdx.x >> 2;        // plane 0..1343
    const int sub = blockIdx.x & 3;         // row segment [sub*64, sub*64+64)
    const int t   = threadIdx.x;

    const int r = x[2 * p];                 // scalar (uniform) loads
    const int c = x[2 * p + 1];

    vfloat4* seg = out + (size_t)p * F4_PER_PLANE + sub * F4_PER_SEG;

    // ---- phase 1: pure zero stream, no branches ----
#pragma unroll
    for (int ch = 0; ch < F4_PER_THREAD; ++ch)
        seg[ch * THREADS + t] = (vfloat4)0.0f;   // wave writes 1 KiB/store

    __syncthreads();

    // ---- phase 2: patch overwrite (<=81 scalar stores per plane) ----
    if (t < KS * KS) {
        const int dy = t / KS;              // 0..8
        const int dx = t - dy * KS;
        const int i  = r - PADK + dy;
        const int j  = c - PADK + dx;
        const int row_lo = sub * (HH / BLOCKS_PER_PLANE);
        if (i >= row_lo && i < row_lo + (HH / BLOCKS_PER_PLANE) &&
            i >= 0 && i < HH && j >= 0 && j < HH) {
            const float v = 10.0f * k2d[(KS - 1 - dy) * KS + (KS - 1 - dx)];
            float* plane = (float*)(out + (size_t)p * F4_PER_PLANE);
            plane[i * HH + j] = v;
        }
    }
}

extern "C" void kernel_launch(void* const* d_in, const int* in_sizes, int n_in,
                              void* d_out, int out_size, void* d_ws, size_t ws_size,
                              hipStream_t stream) {
    const int*   x   = (const int*)d_in[0];    // [B, KP, 2] int32
    const float* k2d = (const float*)d_in[1];  // [KS, KS] float32
    vfloat4*     out = (vfloat4*)d_out;        // [B, KP, H, H] float32

    heatmap_fused2_kernel<<<NPLANES * BLOCKS_PER_PLANE, THREADS, 0, stream>>>(x, k2d, out);
}

// Round 6
// 68.099 us; speedup vs baseline: 1.0744x; 1.0031x over previous
//
#include <hip/hip_runtime.h>

// Problem constants (from reference init_kwargs)
#define BB   64
#define KP   21
#define HH   256
#define KS   9
#define PADK 4   // KS/2

#define NPLANES       (BB * KP)            // 1344
#define F4_PER_PLANE  (HH * HH / 4)        // 16384 float4 per plane
#define NBLOCKS       2048                 // 8 blocks/CU * 256 CU -> 32 waves/CU
#define THREADS       256
#define F4_TOTAL      (NPLANES * F4_PER_PLANE)        // 22,020,096
#define F4_PER_BLOCK  (F4_TOTAL / NBLOCKS)            // 10752
#define F4_PER_THREAD (F4_PER_BLOCK / THREADS)        // 42

typedef float vfloat4 __attribute__((ext_vector_type(4)));

// Persistent fused zero + patch: 2048 blocks, each owns one contiguous
// 168 KB slice. Phase 1: branch-free zero stream (42 dwordx4 stores/thread).
// Phase 2: __syncthreads (vmcnt(0) drain per wave orders zero stores), then
// overwrite the <=81 patch elements of each plane overlapping this slice,
// restricted to addresses inside the slice (so every address is ordered
// within one block; a patch spanning two slices is split between them).
__global__ __launch_bounds__(THREADS)
void heatmap_persist_kernel(const int* __restrict__ x,
                            const float* __restrict__ k2d,
                            vfloat4* __restrict__ out) {
    const int t  = threadIdx.x;
    const int b0 = blockIdx.x * F4_PER_BLOCK;          // first float4 of slice

    // ---- phase 1: pure zero stream ----
    vfloat4* ptr = out + b0 + t;
#pragma unroll
    for (int ch = 0; ch < F4_PER_THREAD; ++ch) {
        *ptr = (vfloat4)0.0f;                          // wave: 1 KiB/store
        ptr += THREADS;
    }

    __syncthreads();

    // ---- phase 2: patch overwrite within this slice ----
    const int p_lo = b0 / F4_PER_PLANE;
    const int p_hi = (b0 + F4_PER_BLOCK - 1) / F4_PER_PLANE;   // <= p_lo+1

    if (t < KS * KS) {
        const int dy = t / KS;                         // 0..8
        const int dx = t - dy * KS;
        for (int p = p_lo; p <= p_hi; ++p) {
            const int r = x[2 * p];
            const int c = x[2 * p + 1];
            const int i = r - PADK + dy;
            const int j = c - PADK + dx;
            if (i < 0 || i >= HH || j < 0 || j >= HH) continue;
            const int g4 = p * F4_PER_PLANE + i * (HH / 4) + (j >> 2);
            if (g4 < b0 || g4 >= b0 + F4_PER_BLOCK) continue;  // not my slice
            const float v = 10.0f * k2d[(KS - 1 - dy) * KS + (KS - 1 - dx)];
            ((float*)out)[(size_t)g4 * 4 + (j & 3)] = v;
        }
    }
}

extern "C" void kernel_launch(void* const* d_in, const int* in_sizes, int n_in,
                              void* d_out, int out_size, void* d_ws, size_t ws_size,
                              hipStream_t stream) {
    const int*   x   = (const int*)d_in[0];    // [B, KP, 2] int32
    const float* k2d = (const float*)d_in[1];  // [KS, KS] float32
    vfloat4*     out = (vfloat4*)d_out;        // [B, KP, H, H] float32

    heatmap_persist_kernel<<<NBLOCKS, THREADS, 0, stream>>>(x, k2d, out);
}